// Round 11
// baseline (495.448 us; speedup 1.0000x reference)
//
#include <hip/hip_runtime.h>
#include <hip/hip_bf16.h>
#include <cstddef>

// ---------------- problem constants ----------------
#define NTOK   64
#define CDIM   192
#define HEADS  6
#define NTHR   384     // 6 waves; wave = head (whole window)
#define SCALE  0.17677669529663687f   // 1/sqrt(32)

#define WQ_ELEMS (3*CDIM*CDIM)   // 110592
#define WP_ELEMS (CDIM*CDIM)     // 36864
#define RELB_ELEMS (HEADS*NTOK*NTOK)          // 24576
#define WS_RELB_OFF ((WQ_ELEMS+WP_ELEMS)*2)   // 294912 B
#define WS_NEED (WS_RELB_OFF + RELB_ELEMS*4)  // 393216 B

typedef __attribute__((ext_vector_type(8))) short bf16x8;
typedef __attribute__((ext_vector_type(4))) float f32x4;
typedef __attribute__((ext_vector_type(4))) unsigned int u32x4;

static __device__ __forceinline__ unsigned short f2b(float f) {
    __hip_bfloat16 h = __float2bfloat16(f);
    return __builtin_bit_cast(unsigned short, h);
}
static __device__ __forceinline__ char* swz384(char* base, int row, int b) {
    return base + ((row * 384 + b) ^ ((row & 7) << 4));
}

static __device__ __forceinline__ uint2 packq4(f32x4 v, float4 b) {
    unsigned short e0 = f2b(v[0] + b.x), e1 = f2b(v[1] + b.y);
    unsigned short e2 = f2b(v[2] + b.z), e3 = f2b(v[3] + b.w);
    uint2 q; q.x = (unsigned)e0 | ((unsigned)e1 << 16);
             q.y = (unsigned)e2 | ((unsigned)e3 << 16);
    return q;
}
static __device__ __forceinline__ uint2 packqs(f32x4 v, float b) {
    unsigned short e0 = f2b(v[0] + b), e1 = f2b(v[1] + b);
    unsigned short e2 = f2b(v[2] + b), e3 = f2b(v[3] + b);
    uint2 q; q.x = (unsigned)e0 | ((unsigned)e1 << 16);
             q.y = (unsigned)e2 | ((unsigned)e3 << 16);
    return q;
}
static __device__ __forceinline__ uint2 packq0(f32x4 v) {
    unsigned short e0 = f2b(v[0]), e1 = f2b(v[1]);
    unsigned short e2 = f2b(v[2]), e3 = f2b(v[3]);
    uint2 q; q.x = (unsigned)e0 | ((unsigned)e1 << 16);
             q.y = (unsigned)e2 | ((unsigned)e3 << 16);
    return q;
}

// hi-group 4x4 quad transpose among lanes {lo, lo+16, lo+32, lo+48}.
// in: a = quad(hi), b = quad(4+hi).  out: oa = quad(2hi), ob = quad(2hi+1).
static __device__ __forceinline__ void p8(uint2 a, uint2 b, int lo, int hi,
                                          uint2& oa, uint2& ob) {
    int sA = lo + ((hi & 1) << 5);
    int sB = sA + 16;
    uint2 Aa, Ab, Ba, Bb;
    Aa.x = (unsigned)__shfl((int)a.x, sA); Aa.y = (unsigned)__shfl((int)a.y, sA);
    Ab.x = (unsigned)__shfl((int)b.x, sA); Ab.y = (unsigned)__shfl((int)b.y, sA);
    Ba.x = (unsigned)__shfl((int)a.x, sB); Ba.y = (unsigned)__shfl((int)a.y, sB);
    Bb.x = (unsigned)__shfl((int)b.x, sB); Bb.y = (unsigned)__shfl((int)b.y, sB);
    oa = (hi < 2) ? Aa : Ab;
    ob = (hi < 2) ? Ba : Bb;
}
static __device__ __forceinline__ bf16x8 mkfrag(uint2 oa, uint2 ob) {
    u32x4 u; u[0] = oa.x; u[1] = oa.y; u[2] = ob.x; u[3] = ob.y;
    return __builtin_bit_cast(bf16x8, u);
}

// ---------------- prep: weights -> bf16; optional relb[h][n][m] table ----------------
__global__ __launch_bounds__(256)
void prep_weights(const float* __restrict__ qkv_w, const float* __restrict__ proj_w,
                  const float* __restrict__ bias_table,
                  unsigned short* __restrict__ wq, unsigned short* __restrict__ wp,
                  float* __restrict__ relb, int fill_relb)
{
    int i = blockIdx.x * 256 + threadIdx.x;
    if (i < WQ_ELEMS) {
        float v = qkv_w[i];
        if (i < CDIM * CDIM) v *= SCALE;
        wq[i] = f2b(v);
    }
    if (i < WP_ELEMS) wp[i] = f2b(proj_w[i]);
    if (fill_relb && i < RELB_ELEMS) {
        int h = i >> 12;
        int rem = i & 4095;
        int n = rem >> 6, m = rem & 63;
        int i1 = n >> 3, j1 = n & 7, i2 = m >> 3, j2 = m & 7;
        relb[i] = bias_table[((i1 - i2 + 7) * 15 + (j1 - j2 + 7)) * HEADS + h];
    }
}

// ---------------- fused: block = window, 6 waves = 6 heads, K/V/Q in registers ----------------
// Only LDS: XA (X, later AO). Barriers: b0 (X staged), b2 (XA reads done),
// b3 (AO complete). Between b0 and b3 each wave is fully independent.
template <bool USE_RELB>
__global__ __launch_bounds__(NTHR, 3)
void win_attn(const float* __restrict__ x,
              const float* __restrict__ mask,
              const unsigned short* __restrict__ wq,
              const float* __restrict__ qkv_b,
              const unsigned short* __restrict__ wp,
              const float* __restrict__ proj_b,
              const float* __restrict__ bias_table,
              const float* __restrict__ relb,
              float* __restrict__ out)
{
    __shared__ __align__(16) char XA[24576];   // [64][192] bf16 swz384; X -> AO

    const int t  = threadIdx.x;
    const int w  = blockIdx.x;
    const int h  = t >> 6;        // wave == head
    const int l  = t & 63;
    const int lo = l & 15;
    const int hi = l >> 4;

    // ---- phase 0: stage X (fp32->bf16 swz384) ----
    const float* xw = x + (size_t)w * (NTOK * CDIM);
    #pragma unroll
    for (int it = 0; it < 4; ++it) {
        int c  = t + it * NTHR;            // 1536 chunks of 8 floats
        int n  = c / 24;
        int cb = (c % 24) * 8;
        float4 v0 = *(const float4*)(xw + c * 8);
        float4 v1 = *(const float4*)(xw + c * 8 + 4);
        bf16x8 p;
        p[0] = (short)f2b(v0.x); p[1] = (short)f2b(v0.y);
        p[2] = (short)f2b(v0.z); p[3] = (short)f2b(v0.w);
        p[4] = (short)f2b(v1.x); p[5] = (short)f2b(v1.y);
        p[6] = (short)f2b(v1.z); p[7] = (short)f2b(v1.w);
        *(bf16x8*)swz384(XA, n, cb * 2) = p;
    }
    __syncthreads();   // b0

    const int tq = 2 * h, tk = 12 + 2 * h, tv = 24 + 2 * h;

    // ---- pass K (swapped: D[o][n]) -> Kf regs via p8; accumulator dies ----
    bf16x8 Kf[4];
    {
        f32x4 ak[2][4] = {};
        for (int ks = 0; ks < 6; ++ks) {
            bf16x8 xf[4];
            #pragma unroll
            for (int nt = 0; nt < 4; ++nt)
                xf[nt] = *(const bf16x8*)swz384(XA, nt * 16 + lo, (ks * 32 + hi * 8) * 2);
            bf16x8 wf[2];
            #pragma unroll
            for (int j = 0; j < 2; ++j)
                wf[j] = *(const bf16x8*)(const void*)(wq + ((tk + j) * 16 + lo) * CDIM + ks * 32 + hi * 8);
            #pragma unroll
            for (int j = 0; j < 2; ++j)
                #pragma unroll
                for (int nt = 0; nt < 4; ++nt)
                    ak[j][nt] = __builtin_amdgcn_mfma_f32_16x16x32_bf16(wf[j], xf[nt], ak[j][nt], 0, 0, 0);
        }
        float4 bk0 = *(const float4*)(qkv_b + tk * 16 + hi * 4);
        float4 bk1 = *(const float4*)(qkv_b + (tk + 1) * 16 + hi * 4);
        #pragma unroll
        for (int mt = 0; mt < 4; ++mt) {
            uint2 oa, ob;
            p8(packq4(ak[0][mt], bk0), packq4(ak[1][mt], bk1), lo, hi, oa, ob);
            Kf[mt] = mkfrag(oa, ob);
        }
    }

    // ---- pass V (normal: D[n][d]) -> Vf regs via p8 ----
    bf16x8 Vf[2][2];
    {
        f32x4 av[4][2] = {};
        for (int ks = 0; ks < 6; ++ks) {
            bf16x8 xf[4];
            #pragma unroll
            for (int nt = 0; nt < 4; ++nt)
                xf[nt] = *(const bf16x8*)swz384(XA, nt * 16 + lo, (ks * 32 + hi * 8) * 2);
            bf16x8 wf[2];
            #pragma unroll
            for (int j = 0; j < 2; ++j)
                wf[j] = *(const bf16x8*)(const void*)(wq + ((tv + j) * 16 + lo) * CDIM + ks * 32 + hi * 8);
            #pragma unroll
            for (int nt = 0; nt < 4; ++nt)
                #pragma unroll
                for (int j = 0; j < 2; ++j)
                    av[nt][j] = __builtin_amdgcn_mfma_f32_16x16x32_bf16(xf[nt], wf[j], av[nt][j], 0, 0, 0);
        }
        float bv0 = qkv_b[tv * 16 + lo];
        float bv1 = qkv_b[(tv + 1) * 16 + lo];
        #pragma unroll
        for (int dt = 0; dt < 2; ++dt) {
            float bv = dt ? bv1 : bv0;
            uint2 oa, ob;
            p8(packqs(av[0][dt], bv), packqs(av[1][dt], bv), lo, hi, oa, ob);
            Vf[0][dt] = mkfrag(oa, ob);
            p8(packqs(av[2][dt], bv), packqs(av[3][dt], bv), lo, hi, oa, ob);
            Vf[1][dt] = mkfrag(oa, ob);
        }
    }

    // ---- pass Q (swapped) -> Qf regs, scale folded ----
    bf16x8 Qf[4];
    {
        f32x4 aq[2][4] = {};
        for (int ks = 0; ks < 6; ++ks) {
            bf16x8 xf[4];
            #pragma unroll
            for (int nt = 0; nt < 4; ++nt)
                xf[nt] = *(const bf16x8*)swz384(XA, nt * 16 + lo, (ks * 32 + hi * 8) * 2);
            bf16x8 wf[2];
            #pragma unroll
            for (int j = 0; j < 2; ++j)
                wf[j] = *(const bf16x8*)(const void*)(wq + ((tq + j) * 16 + lo) * CDIM + ks * 32 + hi * 8);
            #pragma unroll
            for (int j = 0; j < 2; ++j)
                #pragma unroll
                for (int nt = 0; nt < 4; ++nt)
                    aq[j][nt] = __builtin_amdgcn_mfma_f32_16x16x32_bf16(wf[j], xf[nt], aq[j][nt], 0, 0, 0);
        }
        float4 bq0 = *(const float4*)(qkv_b + tq * 16 + hi * 4);
        float4 bq1 = *(const float4*)(qkv_b + (tq + 1) * 16 + hi * 4);
        bq0.x *= SCALE; bq0.y *= SCALE; bq0.z *= SCALE; bq0.w *= SCALE;
        bq1.x *= SCALE; bq1.y *= SCALE; bq1.z *= SCALE; bq1.w *= SCALE;
        #pragma unroll
        for (int nt = 0; nt < 4; ++nt) {
            uint2 oa, ob;
            p8(packq4(aq[0][nt], bq0), packq4(aq[1][nt], bq1), lo, hi, oa, ob);
            Qf[nt] = mkfrag(oa, ob);
        }
    }
    __syncthreads();   // b2: all XA reads done block-wide; AO overlay is now safe

    // ---- QK^T: S^T = K.Q^T + bias + mask (C-init from global) ----
    const float* mw = mask + (size_t)w * (NTOK * NTOK);
    const float* rb = relb + h * (NTOK * NTOK);
    f32x4 cs[4][4];
    #pragma unroll
    for (int nt = 0; nt < 4; ++nt) {
        int n = nt * 16 + lo;
        #pragma unroll
        for (int mt = 0; mt < 4; ++mt) {
            float4 mv = *(const float4*)(mw + n * 64 + mt * 16 + hi * 4);
            if constexpr (USE_RELB) {
                float4 bv = *(const float4*)(rb + n * 64 + mt * 16 + hi * 4);
                cs[mt][nt][0] = mv.x + bv.x;
                cs[mt][nt][1] = mv.y + bv.y;
                cs[mt][nt][2] = mv.z + bv.z;
                cs[mt][nt][3] = mv.w + bv.w;
            } else {
                int i1 = n >> 3, j1 = n & 7;
                float mvr[4] = {mv.x, mv.y, mv.z, mv.w};
                #pragma unroll
                for (int r = 0; r < 4; ++r) {
                    int m  = mt * 16 + hi * 4 + r;
                    int i2 = m >> 3, j2 = m & 7;
                    cs[mt][nt][r] = bias_table[((i1 - i2 + 7) * 15 + (j1 - j2 + 7)) * HEADS + h]
                                  + mvr[r];
                }
            }
        }
    }
    #pragma unroll
    for (int mt = 0; mt < 4; ++mt)
        #pragma unroll
        for (int nt = 0; nt < 4; ++nt)
            cs[mt][nt] = __builtin_amdgcn_mfma_f32_16x16x32_bf16(Kf[mt], Qf[nt], cs[mt][nt], 0, 0, 0);

    // ---- softmax over m per column n; normalization deferred ----
    float iv[4];
    #pragma unroll
    for (int nt = 0; nt < 4; ++nt) {
        float mx = cs[0][nt][0];
        #pragma unroll
        for (int mt = 0; mt < 4; ++mt)
            #pragma unroll
            for (int r = 0; r < 4; ++r) mx = fmaxf(mx, cs[mt][nt][r]);
        mx = fmaxf(mx, __shfl_xor(mx, 16));
        mx = fmaxf(mx, __shfl_xor(mx, 32));
        float s = 0.f;
        #pragma unroll
        for (int mt = 0; mt < 4; ++mt)
            #pragma unroll
            for (int r = 0; r < 4; ++r) {
                float e = __expf(cs[mt][nt][r] - mx);
                cs[mt][nt][r] = e;
                s += e;
            }
        s += __shfl_xor(s, 16);
        s += __shfl_xor(s, 32);
        iv[nt] = 1.0f / s;
    }

    // ---- PV: progressive P-frags x register-resident Vf; shuffle-scale by iv ----
    f32x4 co[4][2] = {};
    #pragma unroll
    for (int ks = 0; ks < 2; ++ks) {
        bf16x8 pfrag[4];
        #pragma unroll
        for (int nt = 0; nt < 4; ++nt) {
            uint2 oa, ob;
            p8(packq0(cs[2 * ks][nt]), packq0(cs[2 * ks + 1][nt]), lo, hi, oa, ob);
            pfrag[nt] = mkfrag(oa, ob);
        }
        #pragma unroll
        for (int nt = 0; nt < 4; ++nt)
            #pragma unroll
            for (int dt = 0; dt < 2; ++dt)
                co[nt][dt] = __builtin_amdgcn_mfma_f32_16x16x32_bf16(pfrag[nt], Vf[ks][dt], co[nt][dt], 0, 0, 0);
    }
    #pragma unroll
    for (int nt = 0; nt < 4; ++nt)
        #pragma unroll
        for (int r = 0; r < 4; ++r) {
            float sc = __shfl(iv[nt], hi * 4 + r);
            co[nt][0][r] *= sc;
            co[nt][1][r] *= sc;
        }

    // ---- AO overlays XA (b2 already passed; own-wave slice, no conflicts) ----
    #pragma unroll
    for (int nt = 0; nt < 4; ++nt)
        #pragma unroll
        for (int dt = 0; dt < 2; ++dt)
            #pragma unroll
            for (int r = 0; r < 4; ++r) {
                int n = nt * 16 + hi * 4 + r;
                *(unsigned short*)swz384(XA, n, (h * 32 + dt * 16 + lo) * 2) =
                    f2b(co[nt][dt][r]);
            }
    __syncthreads();   // b3: AO complete

    // ---- proj: out = AO . Wp^T + b (wave owns 2 o-tiles) ----
    f32x4 ac[4][2] = {};
    for (int ks = 0; ks < 6; ++ks) {
        bf16x8 aa[4];
        #pragma unroll
        for (int nt = 0; nt < 4; ++nt)
            aa[nt] = *(const bf16x8*)swz384(XA, nt * 16 + lo, (ks * 32 + hi * 8) * 2);
        bf16x8 bb[2];
        #pragma unroll
        for (int j = 0; j < 2; ++j)
            bb[j] = *(const bf16x8*)(const void*)(wp + ((h * 2 + j) * 16 + lo) * CDIM + ks * 32 + hi * 8);
        #pragma unroll
        for (int nt = 0; nt < 4; ++nt)
            #pragma unroll
            for (int j = 0; j < 2; ++j)
                ac[nt][j] = __builtin_amdgcn_mfma_f32_16x16x32_bf16(aa[nt], bb[j], ac[nt][j], 0, 0, 0);
    }
    float* outW = out + (size_t)w * (NTOK * CDIM);
    #pragma unroll
    for (int j = 0; j < 2; ++j) {
        int o2 = (h * 2 + j) * 16 + lo;
        float pb = proj_b[o2];
        #pragma unroll
        for (int nt = 0; nt < 4; ++nt)
            #pragma unroll
            for (int r = 0; r < 4; ++r) {
                int n = nt * 16 + hi * 4 + r;
                outW[n * CDIM + o2] = ac[nt][j][r] + pb;
            }
    }
}

extern "C" void kernel_launch(void* const* d_in, const int* in_sizes, int n_in,
                              void* d_out, int out_size, void* d_ws, size_t ws_size,
                              hipStream_t stream) {
    const float* x          = (const float*)d_in[0];
    const float* mask       = (const float*)d_in[1];
    const float* qkv_w      = (const float*)d_in[2];
    const float* qkv_b      = (const float*)d_in[3];
    const float* proj_w     = (const float*)d_in[4];
    const float* proj_b     = (const float*)d_in[5];
    const float* bias_table = (const float*)d_in[6];
    float* out = (float*)d_out;

    unsigned short* wq = (unsigned short*)d_ws;
    unsigned short* wp = wq + WQ_ELEMS;
    float* relb = (float*)((char*)d_ws + WS_RELB_OFF);

    const int nW = in_sizes[0] / (NTOK * CDIM);   // 4096
    const int use_relb = (ws_size >= (size_t)WS_NEED) ? 1 : 0;

    prep_weights<<<dim3((WQ_ELEMS + 255) / 256), dim3(256), 0, stream>>>(
        qkv_w, proj_w, bias_table, wq, wp, relb, use_relb);

    if (use_relb) {
        win_attn<true><<<dim3(nW), dim3(NTHR), 0, stream>>>(
            x, mask, wq, qkv_b, wp, proj_b, bias_table, relb, out);
    } else {
        win_attn<false><<<dim3(nW), dim3(NTHR), 0, stream>>>(
            x, mask, wq, qkv_b, wp, proj_b, bias_table, relb, out);
    }
}

// Round 12
// 390.319 us; speedup vs baseline: 1.2693x; 1.2693x over previous
//
#include <hip/hip_runtime.h>
#include <hip/hip_bf16.h>
#include <cstddef>

// ---------------- problem constants ----------------
#define NTOK   64
#define CDIM   192
#define HEADS  6
#define NTHR   768     // 12 waves; wave = (head, token-half)
#define SCALE  0.17677669529663687f   // 1/sqrt(32)

#define WQ_ELEMS (3*CDIM*CDIM)   // 110592
#define WP_ELEMS (CDIM*CDIM)     // 36864
#define RELB_ELEMS (HEADS*NTOK*NTOK)          // 24576
#define WS_RELB_OFF ((WQ_ELEMS+WP_ELEMS)*2)   // 294912 B
#define WS_NEED (WS_RELB_OFF + RELB_ELEMS*4)  // 393216 B

// LDS byte offsets:
//  XA [64][192] bf16 swz384 (24576) -> becomes AO
//  Kh 6 x [64][32] bf16 swz64  (24576)
//  Vt 6 x [32][64] bf16 swz128 (24576)
#define OFF_K    24576
#define OFF_V    49152
#define LDS_BYTES 73728   // <= 80KB -> 2 blocks/CU

typedef __attribute__((ext_vector_type(8))) short bf16x8;
typedef __attribute__((ext_vector_type(4))) short bf16x4;
typedef __attribute__((ext_vector_type(4))) float f32x4;
typedef __attribute__((ext_vector_type(4))) unsigned int u32x4;

static __device__ __forceinline__ unsigned short f2b(float f) {
    __hip_bfloat16 h = __float2bfloat16(f);
    return __builtin_bit_cast(unsigned short, h);
}
static __device__ __forceinline__ char* swz384(char* base, int row, int b) {
    return base + ((row * 384 + b) ^ ((row & 7) << 4));
}
static __device__ __forceinline__ char* swz64(char* base, int row, int b) {
    return base + row * 64 + (b ^ (((row >> 1) & 3) << 4));
}
static __device__ __forceinline__ char* swz128(char* base, int row, int b) {
    return base + ((row * 128 + b) ^ ((row & 7) << 4));
}

static __device__ __forceinline__ uint2 packq4(f32x4 v, float4 b) {
    unsigned short e0 = f2b(v[0] + b.x), e1 = f2b(v[1] + b.y);
    unsigned short e2 = f2b(v[2] + b.z), e3 = f2b(v[3] + b.w);
    uint2 q; q.x = (unsigned)e0 | ((unsigned)e1 << 16);
             q.y = (unsigned)e2 | ((unsigned)e3 << 16);
    return q;
}
static __device__ __forceinline__ uint2 packq0(f32x4 v) {
    unsigned short e0 = f2b(v[0]), e1 = f2b(v[1]);
    unsigned short e2 = f2b(v[2]), e3 = f2b(v[3]);
    uint2 q; q.x = (unsigned)e0 | ((unsigned)e1 << 16);
             q.y = (unsigned)e2 | ((unsigned)e3 << 16);
    return q;
}

// hi-group 4x4 quad transpose among lanes {lo, lo+16, lo+32, lo+48}.
static __device__ __forceinline__ void p8(uint2 a, uint2 b, int lo, int hi,
                                          uint2& oa, uint2& ob) {
    int sA = lo + ((hi & 1) << 5);
    int sB = sA + 16;
    uint2 Aa, Ab, Ba, Bb;
    Aa.x = (unsigned)__shfl((int)a.x, sA); Aa.y = (unsigned)__shfl((int)a.y, sA);
    Ab.x = (unsigned)__shfl((int)b.x, sA); Ab.y = (unsigned)__shfl((int)b.y, sA);
    Ba.x = (unsigned)__shfl((int)a.x, sB); Ba.y = (unsigned)__shfl((int)a.y, sB);
    Bb.x = (unsigned)__shfl((int)b.x, sB); Bb.y = (unsigned)__shfl((int)b.y, sB);
    oa = (hi < 2) ? Aa : Ab;
    ob = (hi < 2) ? Ba : Bb;
}
static __device__ __forceinline__ bf16x8 mkfrag(uint2 oa, uint2 ob) {
    u32x4 u; u[0] = oa.x; u[1] = oa.y; u[2] = ob.x; u[3] = ob.y;
    return __builtin_bit_cast(bf16x8, u);
}

// ---------------- prep: weights -> bf16; optional relb[h][n][m] table ----------------
__global__ __launch_bounds__(256)
void prep_weights(const float* __restrict__ qkv_w, const float* __restrict__ proj_w,
                  const float* __restrict__ bias_table,
                  unsigned short* __restrict__ wq, unsigned short* __restrict__ wp,
                  float* __restrict__ relb, int fill_relb)
{
    int i = blockIdx.x * 256 + threadIdx.x;
    if (i < WQ_ELEMS) {
        float v = qkv_w[i];
        if (i < CDIM * CDIM) v *= SCALE;
        wq[i] = f2b(v);
    }
    if (i < WP_ELEMS) wp[i] = f2b(proj_w[i]);
    if (fill_relb && i < RELB_ELEMS) {
        int h = i >> 12;
        int rem = i & 4095;
        int n = rem >> 6, m = rem & 63;
        int i1 = n >> 3, j1 = n & 7, i2 = m >> 3, j2 = m & 7;
        relb[i] = bias_table[((i1 - i2 + 7) * 15 + (j1 - j2 + 7)) * HEADS + h];
    }
}

// ---------------- fused: block = window, 12 waves = (head, half) ----------------
// Pass order Q,K,V then ONE barrier (b1): it means both "K/V visible" and
// "all XA reads complete", so the attention tail (QK^T/softmax/PV/AO-write)
// runs per-wave with no further sync until b2 before proj. Waves de-phase
// after b1 -> setprio around MFMA clusters pays (role diversity).
template <bool USE_RELB>
__global__ __launch_bounds__(NTHR, 6)
void win_attn(const float* __restrict__ x,
              const float* __restrict__ mask,
              const unsigned short* __restrict__ wq,
              const float* __restrict__ qkv_b,
              const unsigned short* __restrict__ wp,
              const float* __restrict__ proj_b,
              const float* __restrict__ bias_table,
              const float* __restrict__ relb,
              float* __restrict__ out)
{
    extern __shared__ char smem[];
    char* XA = smem;

    const int t    = threadIdx.x;
    const int w    = blockIdx.x;
    const int wv   = t >> 6;
    const int h    = wv >> 1;       // head
    const int half = wv & 1;        // token half
    const int l    = t & 63;
    const int lo   = l & 15;
    const int hi   = l >> 4;

    char* Kh = smem + OFF_K + h * 4096;   // [64 m][32 d] bf16 swz64
    char* Vh = smem + OFF_V + h * 4096;   // Vt [32 d][64 m] bf16 swz128

    // ---- phase 0: stage X (fp32->bf16 swz384) ----
    const float* xw = x + (size_t)w * (NTOK * CDIM);
    #pragma unroll
    for (int it = 0; it < 2; ++it) {
        int c  = t + it * NTHR;            // 1536 chunks of 8 floats
        int n  = c / 24;
        int cb = (c % 24) * 8;
        float4 v0 = *(const float4*)(xw + c * 8);
        float4 v1 = *(const float4*)(xw + c * 8 + 4);
        bf16x8 p;
        p[0] = (short)f2b(v0.x); p[1] = (short)f2b(v0.y);
        p[2] = (short)f2b(v0.z); p[3] = (short)f2b(v0.w);
        p[4] = (short)f2b(v1.x); p[5] = (short)f2b(v1.y);
        p[6] = (short)f2b(v1.z); p[7] = (short)f2b(v1.w);
        *(bf16x8*)swz384(XA, n, cb * 2) = p;
    }
    __syncthreads();   // b0: X staged

    const int tq = 2 * h, tk = 12 + 2 * h, tv = 24 + 2 * h;

    // ---- pass Q -> Qf regs (held across K/V passes; 16 arch-VGPRs) ----
    bf16x8 Qf[2];
    {
        f32x4 aq[2][2] = {};
        for (int ks = 0; ks < 6; ++ks) {
            bf16x8 xf[2];
            #pragma unroll
            for (int ntl = 0; ntl < 2; ++ntl)
                xf[ntl] = *(const bf16x8*)swz384(XA, (half * 2 + ntl) * 16 + lo,
                                                 (ks * 32 + hi * 8) * 2);
            bf16x8 wf[2];
            #pragma unroll
            for (int j = 0; j < 2; ++j)
                wf[j] = *(const bf16x8*)(const void*)(wq + ((tq + j) * 16 + lo) * CDIM + ks * 32 + hi * 8);
            #pragma unroll
            for (int j = 0; j < 2; ++j)
                #pragma unroll
                for (int ntl = 0; ntl < 2; ++ntl)
                    aq[j][ntl] = __builtin_amdgcn_mfma_f32_16x16x32_bf16(wf[j], xf[ntl], aq[j][ntl], 0, 0, 0);
        }
        float4 bq0 = *(const float4*)(qkv_b + tq * 16 + hi * 4);
        float4 bq1 = *(const float4*)(qkv_b + (tq + 1) * 16 + hi * 4);
        bq0.x *= SCALE; bq0.y *= SCALE; bq0.z *= SCALE; bq0.w *= SCALE;
        bq1.x *= SCALE; bq1.y *= SCALE; bq1.z *= SCALE; bq1.w *= SCALE;
        #pragma unroll
        for (int ntl = 0; ntl < 2; ++ntl) {
            uint2 oa, ob;
            p8(packq4(aq[0][ntl], bq0), packq4(aq[1][ntl], bq1), lo, hi, oa, ob);
            Qf[ntl] = mkfrag(oa, ob);
        }
    }

    // ---- pass K: accumulator -> LDS, dies ----
    {
        f32x4 ak[2][2] = {};
        for (int ks = 0; ks < 6; ++ks) {
            bf16x8 xf[2];
            #pragma unroll
            for (int ntl = 0; ntl < 2; ++ntl)
                xf[ntl] = *(const bf16x8*)swz384(XA, (half * 2 + ntl) * 16 + lo,
                                                 (ks * 32 + hi * 8) * 2);
            bf16x8 wf[2];
            #pragma unroll
            for (int j = 0; j < 2; ++j)
                wf[j] = *(const bf16x8*)(const void*)(wq + ((tk + j) * 16 + lo) * CDIM + ks * 32 + hi * 8);
            #pragma unroll
            for (int j = 0; j < 2; ++j)
                #pragma unroll
                for (int ntl = 0; ntl < 2; ++ntl)
                    ak[j][ntl] = __builtin_amdgcn_mfma_f32_16x16x32_bf16(wf[j], xf[ntl], ak[j][ntl], 0, 0, 0);
        }
        #pragma unroll
        for (int j = 0; j < 2; ++j) {
            float4 bk = *(const float4*)(qkv_b + (tk + j) * 16 + hi * 4);
            float bkr[4] = {bk.x, bk.y, bk.z, bk.w};
            #pragma unroll
            for (int mtl = 0; mtl < 2; ++mtl) {
                int m = (half * 2 + mtl) * 16 + lo;
                bf16x4 pk;
                #pragma unroll
                for (int r = 0; r < 4; ++r) pk[r] = (short)f2b(ak[j][mtl][r] + bkr[r]);
                *(bf16x4*)swz64(Kh, m, j * 32 + hi * 8) = pk;
            }
        }
    }

    // ---- pass V ----
    {
        f32x4 av[2][2] = {};
        for (int ks = 0; ks < 6; ++ks) {
            bf16x8 xf[2];
            #pragma unroll
            for (int ntl = 0; ntl < 2; ++ntl)
                xf[ntl] = *(const bf16x8*)swz384(XA, (half * 2 + ntl) * 16 + lo,
                                                 (ks * 32 + hi * 8) * 2);
            bf16x8 wf[2];
            #pragma unroll
            for (int j = 0; j < 2; ++j)
                wf[j] = *(const bf16x8*)(const void*)(wq + ((tv + j) * 16 + lo) * CDIM + ks * 32 + hi * 8);
            #pragma unroll
            for (int ntl = 0; ntl < 2; ++ntl)
                #pragma unroll
                for (int j = 0; j < 2; ++j)
                    av[ntl][j] = __builtin_amdgcn_mfma_f32_16x16x32_bf16(xf[ntl], wf[j], av[ntl][j], 0, 0, 0);
        }
        #pragma unroll
        for (int mtl = 0; mtl < 2; ++mtl)
            #pragma unroll
            for (int j = 0; j < 2; ++j) {
                float bv = qkv_b[(tv + j) * 16 + lo];
                bf16x4 pv;
                #pragma unroll
                for (int r = 0; r < 4; ++r) pv[r] = (short)f2b(av[mtl][j][r] + bv);
                *(bf16x4*)swz128(Vh, j * 16 + lo, ((half * 2 + mtl) * 16 + hi * 4) * 2) = pv;
            }
    }
    __syncthreads();   // b1: K/V visible AND all XA reads complete

    // ---- QK^T: S^T = K.Q^T + bias + mask (C-init from global) ----
    const float* mw = mask + (size_t)w * (NTOK * NTOK);
    const float* rb = relb + h * (NTOK * NTOK);
    f32x4 cs[4][2];
    #pragma unroll
    for (int ntl = 0; ntl < 2; ++ntl) {
        int n  = (half * 2 + ntl) * 16 + lo;
        #pragma unroll
        for (int mt = 0; mt < 4; ++mt) {
            float4 mv = *(const float4*)(mw + n * 64 + mt * 16 + hi * 4);
            if constexpr (USE_RELB) {
                float4 bv = *(const float4*)(rb + n * 64 + mt * 16 + hi * 4);
                cs[mt][ntl][0] = mv.x + bv.x;
                cs[mt][ntl][1] = mv.y + bv.y;
                cs[mt][ntl][2] = mv.z + bv.z;
                cs[mt][ntl][3] = mv.w + bv.w;
            } else {
                int i1 = n >> 3, j1 = n & 7;
                float mvr[4] = {mv.x, mv.y, mv.z, mv.w};
                #pragma unroll
                for (int r = 0; r < 4; ++r) {
                    int m  = mt * 16 + hi * 4 + r;
                    int i2 = m >> 3, j2 = m & 7;
                    cs[mt][ntl][r] = bias_table[((i1 - i2 + 7) * 15 + (j1 - j2 + 7)) * HEADS + h]
                                   + mvr[r];
                }
            }
        }
    }
    __builtin_amdgcn_s_setprio(1);
    #pragma unroll
    for (int mt = 0; mt < 4; ++mt) {
        bf16x8 Kf = *(const bf16x8*)swz64(Kh, mt * 16 + lo, hi * 16);
        #pragma unroll
        for (int ntl = 0; ntl < 2; ++ntl)
            cs[mt][ntl] = __builtin_amdgcn_mfma_f32_16x16x32_bf16(Kf, Qf[ntl], cs[mt][ntl], 0, 0, 0);
    }
    __builtin_amdgcn_s_setprio(0);

    // ---- softmax over m (per column n); normalization deferred ----
    float iv[2];
    #pragma unroll
    for (int ntl = 0; ntl < 2; ++ntl) {
        float mx = cs[0][ntl][0];
        #pragma unroll
        for (int mt = 0; mt < 4; ++mt)
            #pragma unroll
            for (int r = 0; r < 4; ++r) mx = fmaxf(mx, cs[mt][ntl][r]);
        mx = fmaxf(mx, __shfl_xor(mx, 16));
        mx = fmaxf(mx, __shfl_xor(mx, 32));
        float s = 0.f;
        #pragma unroll
        for (int mt = 0; mt < 4; ++mt)
            #pragma unroll
            for (int r = 0; r < 4; ++r) {
                float e = __expf(cs[mt][ntl][r] - mx);
                cs[mt][ntl][r] = e;
                s += e;
            }
        s += __shfl_xor(s, 16);
        s += __shfl_xor(s, 32);
        iv[ntl] = 1.0f / s;
    }

    // ---- PV with progressive P-frags; then shuffle-scale by iv ----
    f32x4 co[2][2] = {};
    #pragma unroll
    for (int ks = 0; ks < 2; ++ks) {
        bf16x8 pfrag[2];
        #pragma unroll
        for (int ntl = 0; ntl < 2; ++ntl) {
            uint2 oa, ob;
            p8(packq0(cs[2 * ks][ntl]), packq0(cs[2 * ks + 1][ntl]), lo, hi, oa, ob);
            pfrag[ntl] = mkfrag(oa, ob);
        }
        bf16x8 vb[2];
        #pragma unroll
        for (int dt = 0; dt < 2; ++dt)
            vb[dt] = *(const bf16x8*)swz128(Vh, dt * 16 + lo, (ks * 32 + hi * 8) * 2);
        __builtin_amdgcn_s_setprio(1);
        #pragma unroll
        for (int ntl = 0; ntl < 2; ++ntl)
            #pragma unroll
            for (int dt = 0; dt < 2; ++dt)
                co[ntl][dt] = __builtin_amdgcn_mfma_f32_16x16x32_bf16(pfrag[ntl], vb[dt], co[ntl][dt], 0, 0, 0);
        __builtin_amdgcn_s_setprio(0);
    }
    #pragma unroll
    for (int ntl = 0; ntl < 2; ++ntl)
        #pragma unroll
        for (int r = 0; r < 4; ++r) {
            float sc = __shfl(iv[ntl], hi * 4 + r);
            co[ntl][0][r] *= sc;
            co[ntl][1][r] *= sc;
        }

    // ---- AO overlays XA: per-wave disjoint rows(32 of its half) x cols(its head)
    //      b1 guaranteed all XA reads are done; no barrier needed here ----
    #pragma unroll
    for (int ntl = 0; ntl < 2; ++ntl)
        #pragma unroll
        for (int dt = 0; dt < 2; ++dt)
            #pragma unroll
            for (int r = 0; r < 4; ++r) {
                int n = (half * 2 + ntl) * 16 + hi * 4 + r;
                *(unsigned short*)swz384(XA, n, (h * 32 + dt * 16 + lo) * 2) =
                    f2b(co[ntl][dt][r]);
            }
    __syncthreads();   // b2: AO complete

    // ---- proj: out = AO . Wp^T + b (wave owns o-tile wv) ----
    f32x4 ac[4] = {};
    const int o2 = wv * 16 + lo;
    for (int ks = 0; ks < 6; ++ks) {
        bf16x8 bb = *(const bf16x8*)(const void*)(wp + o2 * CDIM + ks * 32 + hi * 8);
        #pragma unroll
        for (int nt = 0; nt < 4; ++nt) {
            bf16x8 aa = *(const bf16x8*)swz384(XA, nt * 16 + lo, (ks * 32 + hi * 8) * 2);
            ac[nt] = __builtin_amdgcn_mfma_f32_16x16x32_bf16(aa, bb, ac[nt], 0, 0, 0);
        }
    }
    float* outW = out + (size_t)w * (NTOK * CDIM);
    float pb = proj_b[o2];
    #pragma unroll
    for (int nt = 0; nt < 4; ++nt)
        #pragma unroll
        for (int r = 0; r < 4; ++r) {
            int n = nt * 16 + hi * 4 + r;
            outW[n * CDIM + o2] = ac[nt][r] + pb;
        }
}

extern "C" void kernel_launch(void* const* d_in, const int* in_sizes, int n_in,
                              void* d_out, int out_size, void* d_ws, size_t ws_size,
                              hipStream_t stream) {
    const float* x          = (const float*)d_in[0];
    const float* mask       = (const float*)d_in[1];
    const float* qkv_w      = (const float*)d_in[2];
    const float* qkv_b      = (const float*)d_in[3];
    const float* proj_w     = (const float*)d_in[4];
    const float* proj_b     = (const float*)d_in[5];
    const float* bias_table = (const float*)d_in[6];
    float* out = (float*)d_out;

    unsigned short* wq = (unsigned short*)d_ws;
    unsigned short* wp = wq + WQ_ELEMS;
    float* relb = (float*)((char*)d_ws + WS_RELB_OFF);

    const int nW = in_sizes[0] / (NTOK * CDIM);   // 4096
    const int use_relb = (ws_size >= (size_t)WS_NEED) ? 1 : 0;

    prep_weights<<<dim3((WQ_ELEMS + 255) / 256), dim3(256), 0, stream>>>(
        qkv_w, proj_w, bias_table, wq, wp, relb, use_relb);

    if (use_relb) {
        hipFuncSetAttribute(reinterpret_cast<const void*>(win_attn<true>),
                            hipFuncAttributeMaxDynamicSharedMemorySize, LDS_BYTES);
        win_attn<true><<<dim3(nW), dim3(NTHR), LDS_BYTES, stream>>>(
            x, mask, wq, qkv_b, wp, proj_b, bias_table, relb, out);
    } else {
        hipFuncSetAttribute(reinterpret_cast<const void*>(win_attn<false>),
                            hipFuncAttributeMaxDynamicSharedMemorySize, LDS_BYTES);
        win_attn<false><<<dim3(nW), dim3(NTHR), LDS_BYTES, stream>>>(
            x, mask, wq, qkv_b, wp, proj_b, bias_table, relb, out);
    }
}

// Round 13
// 368.643 us; speedup vs baseline: 1.3440x; 1.0588x over previous
//
#include <hip/hip_runtime.h>
#include <hip/hip_bf16.h>
#include <cstddef>

// ---------------- problem constants ----------------
#define NTOK   64
#define CDIM   192
#define HEADS  6
#define NTHR   768     // 12 waves; wave = (head, token-half)
#define SCALE  0.17677669529663687f   // 1/sqrt(32)

#define WQ_ELEMS (3*CDIM*CDIM)   // 110592
#define WP_ELEMS (CDIM*CDIM)     // 36864
#define RELB_ELEMS (HEADS*NTOK*NTOK)          // 24576
#define WS_RELB_OFF ((WQ_ELEMS+WP_ELEMS)*2)   // 294912 B
#define WS_NEED (WS_RELB_OFF + RELB_ELEMS*4)  // 393216 B

// LDS byte offsets:
//  XA [64][192] bf16 swz384 (24576) -> becomes AO after phase 3
//  Kh 6 x [64][32] bf16 swz64  (24576)
//  Vt 6 x [32][64] bf16 swz128 (24576)
#define OFF_K    24576
#define OFF_V    49152
#define LDS_BYTES 73728   // <= 80KB -> 2 blocks/CU

typedef __attribute__((ext_vector_type(8))) short bf16x8;
typedef __attribute__((ext_vector_type(4))) short bf16x4;
typedef __attribute__((ext_vector_type(4))) float f32x4;
typedef __attribute__((ext_vector_type(4))) unsigned int u32x4;

static __device__ __forceinline__ unsigned short f2b(float f) {
    __hip_bfloat16 h = __float2bfloat16(f);
    return __builtin_bit_cast(unsigned short, h);
}
static __device__ __forceinline__ char* swz384(char* base, int row, int b) {
    return base + ((row * 384 + b) ^ ((row & 7) << 4));
}
static __device__ __forceinline__ char* swz64(char* base, int row, int b) {
    return base + row * 64 + (b ^ (((row >> 1) & 3) << 4));
}
static __device__ __forceinline__ char* swz128(char* base, int row, int b) {
    return base + ((row * 128 + b) ^ ((row & 7) << 4));
}

static __device__ __forceinline__ uint2 packq4(f32x4 v, float4 b) {
    unsigned short e0 = f2b(v[0] + b.x), e1 = f2b(v[1] + b.y);
    unsigned short e2 = f2b(v[2] + b.z), e3 = f2b(v[3] + b.w);
    uint2 q; q.x = (unsigned)e0 | ((unsigned)e1 << 16);
             q.y = (unsigned)e2 | ((unsigned)e3 << 16);
    return q;
}
static __device__ __forceinline__ uint2 packq0(f32x4 v) {
    unsigned short e0 = f2b(v[0]), e1 = f2b(v[1]);
    unsigned short e2 = f2b(v[2]), e3 = f2b(v[3]);
    uint2 q; q.x = (unsigned)e0 | ((unsigned)e1 << 16);
             q.y = (unsigned)e2 | ((unsigned)e3 << 16);
    return q;
}

// hi-group 4x4 quad transpose among lanes {lo, lo+16, lo+32, lo+48}.
static __device__ __forceinline__ void p8(uint2 a, uint2 b, int lo, int hi,
                                          uint2& oa, uint2& ob) {
    int sA = lo + ((hi & 1) << 5);
    int sB = sA + 16;
    uint2 Aa, Ab, Ba, Bb;
    Aa.x = (unsigned)__shfl((int)a.x, sA); Aa.y = (unsigned)__shfl((int)a.y, sA);
    Ab.x = (unsigned)__shfl((int)b.x, sA); Ab.y = (unsigned)__shfl((int)b.y, sA);
    Ba.x = (unsigned)__shfl((int)a.x, sB); Ba.y = (unsigned)__shfl((int)a.y, sB);
    Bb.x = (unsigned)__shfl((int)b.x, sB); Bb.y = (unsigned)__shfl((int)b.y, sB);
    oa = (hi < 2) ? Aa : Ab;
    ob = (hi < 2) ? Ba : Bb;
}
static __device__ __forceinline__ bf16x8 mkfrag(uint2 oa, uint2 ob) {
    u32x4 u; u[0] = oa.x; u[1] = oa.y; u[2] = ob.x; u[3] = ob.y;
    return __builtin_bit_cast(bf16x8, u);
}

// ---------------- prep: weights -> bf16; optional relb[h][n][m] table ----------------
__global__ __launch_bounds__(256)
void prep_weights(const float* __restrict__ qkv_w, const float* __restrict__ proj_w,
                  const float* __restrict__ bias_table,
                  unsigned short* __restrict__ wq, unsigned short* __restrict__ wp,
                  float* __restrict__ relb, int fill_relb)
{
    int i = blockIdx.x * 256 + threadIdx.x;
    if (i < WQ_ELEMS) {
        float v = qkv_w[i];
        if (i < CDIM * CDIM) v *= SCALE;
        wq[i] = f2b(v);
    }
    if (i < WP_ELEMS) wp[i] = f2b(proj_w[i]);
    if (fill_relb && i < RELB_ELEMS) {
        int h = i >> 12;
        int rem = i & 4095;
        int n = rem >> 6, m = rem & 63;
        int i1 = n >> 3, j1 = n & 7, i2 = m >> 3, j2 = m & 7;
        relb[i] = bias_table[((i1 - i2 + 7) * 15 + (j1 - j2 + 7)) * HEADS + h];
    }
}

// ---------------- fused: block = window, 12 waves = (head, half) ----------------
// Pass order K,V | barrier | Q->QK^T fused: nothing large lives across a phase
// boundary; P-frags built progressively; softmax normalization deferred to a
// post-PV shuffle-scale. Zero spill at the 85-reg cap (2 blocks/CU).
template <bool USE_RELB>
__global__ __launch_bounds__(NTHR, 6)
void win_attn(const float* __restrict__ x,
              const float* __restrict__ mask,
              const unsigned short* __restrict__ wq,
              const float* __restrict__ qkv_b,
              const unsigned short* __restrict__ wp,
              const float* __restrict__ proj_b,
              const float* __restrict__ bias_table,
              const float* __restrict__ relb,
              float* __restrict__ out)
{
    extern __shared__ char smem[];
    char* XA = smem;

    const int t    = threadIdx.x;
    const int w    = blockIdx.x;
    const int wv   = t >> 6;
    const int h    = wv >> 1;       // head
    const int half = wv & 1;        // token half
    const int l    = t & 63;
    const int lo   = l & 15;
    const int hi   = l >> 4;

    char* Kh = smem + OFF_K + h * 4096;   // [64 m][32 d] bf16 swz64
    char* Vh = smem + OFF_V + h * 4096;   // Vt [32 d][64 m] bf16 swz128

    // ---- phase 0: stage X (fp32->bf16 swz384) ----
    const float* xw = x + (size_t)w * (NTOK * CDIM);
    #pragma unroll
    for (int it = 0; it < 2; ++it) {
        int c  = t + it * NTHR;            // 1536 chunks of 8 floats
        int n  = c / 24;
        int cb = (c % 24) * 8;
        float4 v0 = *(const float4*)(xw + c * 8);
        float4 v1 = *(const float4*)(xw + c * 8 + 4);
        bf16x8 p;
        p[0] = (short)f2b(v0.x); p[1] = (short)f2b(v0.y);
        p[2] = (short)f2b(v0.z); p[3] = (short)f2b(v0.w);
        p[4] = (short)f2b(v1.x); p[5] = (short)f2b(v1.y);
        p[6] = (short)f2b(v1.z); p[7] = (short)f2b(v1.w);
        *(bf16x8*)swz384(XA, n, cb * 2) = p;
    }
    __syncthreads();

    const int tq = 2 * h, tk = 12 + 2 * h, tv = 24 + 2 * h;

    // ---- pass K: 32-reg accumulator -> LDS, dies ----
    {
        f32x4 ak[2][2] = {};
        for (int ks = 0; ks < 6; ++ks) {
            bf16x8 xf[2];
            #pragma unroll
            for (int ntl = 0; ntl < 2; ++ntl)
                xf[ntl] = *(const bf16x8*)swz384(XA, (half * 2 + ntl) * 16 + lo,
                                                 (ks * 32 + hi * 8) * 2);
            bf16x8 wf[2];
            #pragma unroll
            for (int j = 0; j < 2; ++j)
                wf[j] = *(const bf16x8*)(const void*)(wq + ((tk + j) * 16 + lo) * CDIM + ks * 32 + hi * 8);
            #pragma unroll
            for (int j = 0; j < 2; ++j)
                #pragma unroll
                for (int ntl = 0; ntl < 2; ++ntl)
                    ak[j][ntl] = __builtin_amdgcn_mfma_f32_16x16x32_bf16(wf[j], xf[ntl], ak[j][ntl], 0, 0, 0);
        }
        #pragma unroll
        for (int j = 0; j < 2; ++j) {
            float4 bk = *(const float4*)(qkv_b + (tk + j) * 16 + hi * 4);
            float bkr[4] = {bk.x, bk.y, bk.z, bk.w};
            #pragma unroll
            for (int mtl = 0; mtl < 2; ++mtl) {
                int m = (half * 2 + mtl) * 16 + lo;
                bf16x4 pk;
                #pragma unroll
                for (int r = 0; r < 4; ++r) pk[r] = (short)f2b(ak[j][mtl][r] + bkr[r]);
                *(bf16x4*)swz64(Kh, m, j * 32 + hi * 8) = pk;
            }
        }
    }

    // ---- pass V ----
    {
        f32x4 av[2][2] = {};
        for (int ks = 0; ks < 6; ++ks) {
            bf16x8 xf[2];
            #pragma unroll
            for (int ntl = 0; ntl < 2; ++ntl)
                xf[ntl] = *(const bf16x8*)swz384(XA, (half * 2 + ntl) * 16 + lo,
                                                 (ks * 32 + hi * 8) * 2);
            bf16x8 wf[2];
            #pragma unroll
            for (int j = 0; j < 2; ++j)
                wf[j] = *(const bf16x8*)(const void*)(wq + ((tv + j) * 16 + lo) * CDIM + ks * 32 + hi * 8);
            #pragma unroll
            for (int ntl = 0; ntl < 2; ++ntl)
                #pragma unroll
                for (int j = 0; j < 2; ++j)
                    av[ntl][j] = __builtin_amdgcn_mfma_f32_16x16x32_bf16(xf[ntl], wf[j], av[ntl][j], 0, 0, 0);
        }
        #pragma unroll
        for (int mtl = 0; mtl < 2; ++mtl)
            #pragma unroll
            for (int j = 0; j < 2; ++j) {
                float bv = qkv_b[(tv + j) * 16 + lo];
                bf16x4 pv;
                #pragma unroll
                for (int r = 0; r < 4; ++r) pv[r] = (short)f2b(av[mtl][j][r] + bv);
                *(bf16x4*)swz128(Vh, j * 16 + lo, ((half * 2 + mtl) * 16 + hi * 4) * 2) = pv;
            }
    }
    __syncthreads();   // b1: K/V visible to both halves

    // ---- pass Q (after b1; XA still intact) -> Qf regs ----
    bf16x8 Qf[2];
    {
        f32x4 aq[2][2] = {};
        for (int ks = 0; ks < 6; ++ks) {
            bf16x8 xf[2];
            #pragma unroll
            for (int ntl = 0; ntl < 2; ++ntl)
                xf[ntl] = *(const bf16x8*)swz384(XA, (half * 2 + ntl) * 16 + lo,
                                                 (ks * 32 + hi * 8) * 2);
            bf16x8 wf[2];
            #pragma unroll
            for (int j = 0; j < 2; ++j)
                wf[j] = *(const bf16x8*)(const void*)(wq + ((tq + j) * 16 + lo) * CDIM + ks * 32 + hi * 8);
            #pragma unroll
            for (int j = 0; j < 2; ++j)
                #pragma unroll
                for (int ntl = 0; ntl < 2; ++ntl)
                    aq[j][ntl] = __builtin_amdgcn_mfma_f32_16x16x32_bf16(wf[j], xf[ntl], aq[j][ntl], 0, 0, 0);
        }
        float4 bq0 = *(const float4*)(qkv_b + tq * 16 + hi * 4);
        float4 bq1 = *(const float4*)(qkv_b + (tq + 1) * 16 + hi * 4);
        bq0.x *= SCALE; bq0.y *= SCALE; bq0.z *= SCALE; bq0.w *= SCALE;
        bq1.x *= SCALE; bq1.y *= SCALE; bq1.z *= SCALE; bq1.w *= SCALE;
        #pragma unroll
        for (int ntl = 0; ntl < 2; ++ntl) {
            uint2 oa, ob;
            p8(packq4(aq[0][ntl], bq0), packq4(aq[1][ntl], bq1), lo, hi, oa, ob);
            Qf[ntl] = mkfrag(oa, ob);
        }
    }

    // ---- QK^T: S^T = K.Q^T + bias + mask (C-init from global) ----
    const float* mw = mask + (size_t)w * (NTOK * NTOK);
    const float* rb = relb + h * (NTOK * NTOK);
    f32x4 cs[4][2];
    #pragma unroll
    for (int ntl = 0; ntl < 2; ++ntl) {
        int n  = (half * 2 + ntl) * 16 + lo;
        #pragma unroll
        for (int mt = 0; mt < 4; ++mt) {
            float4 mv = *(const float4*)(mw + n * 64 + mt * 16 + hi * 4);
            if constexpr (USE_RELB) {
                float4 bv = *(const float4*)(rb + n * 64 + mt * 16 + hi * 4);
                cs[mt][ntl][0] = mv.x + bv.x;
                cs[mt][ntl][1] = mv.y + bv.y;
                cs[mt][ntl][2] = mv.z + bv.z;
                cs[mt][ntl][3] = mv.w + bv.w;
            } else {
                int i1 = n >> 3, j1 = n & 7;
                float mvr[4] = {mv.x, mv.y, mv.z, mv.w};
                #pragma unroll
                for (int r = 0; r < 4; ++r) {
                    int m  = mt * 16 + hi * 4 + r;
                    int i2 = m >> 3, j2 = m & 7;
                    cs[mt][ntl][r] = bias_table[((i1 - i2 + 7) * 15 + (j1 - j2 + 7)) * HEADS + h]
                                   + mvr[r];
                }
            }
        }
    }
    #pragma unroll
    for (int mt = 0; mt < 4; ++mt) {
        bf16x8 Kf = *(const bf16x8*)swz64(Kh, mt * 16 + lo, hi * 16);
        #pragma unroll
        for (int ntl = 0; ntl < 2; ++ntl)
            cs[mt][ntl] = __builtin_amdgcn_mfma_f32_16x16x32_bf16(Kf, Qf[ntl], cs[mt][ntl], 0, 0, 0);
    }

    // ---- softmax over m (per column n); NO normalize (deferred); iv kept ----
    float iv[2];
    #pragma unroll
    for (int ntl = 0; ntl < 2; ++ntl) {
        float mx = cs[0][ntl][0];
        #pragma unroll
        for (int mt = 0; mt < 4; ++mt)
            #pragma unroll
            for (int r = 0; r < 4; ++r) mx = fmaxf(mx, cs[mt][ntl][r]);
        mx = fmaxf(mx, __shfl_xor(mx, 16));
        mx = fmaxf(mx, __shfl_xor(mx, 32));
        float s = 0.f;
        #pragma unroll
        for (int mt = 0; mt < 4; ++mt)
            #pragma unroll
            for (int r = 0; r < 4; ++r) {
                float e = __expf(cs[mt][ntl][r] - mx);
                cs[mt][ntl][r] = e;
                s += e;
            }
        s += __shfl_xor(s, 16);
        s += __shfl_xor(s, 32);
        iv[ntl] = 1.0f / s;
    }

    // ---- PV with progressive P-frags; then shuffle-scale by iv ----
    f32x4 co[2][2] = {};
    #pragma unroll
    for (int ks = 0; ks < 2; ++ks) {
        bf16x8 pfrag[2];
        #pragma unroll
        for (int ntl = 0; ntl < 2; ++ntl) {
            uint2 oa, ob;
            p8(packq0(cs[2 * ks][ntl]), packq0(cs[2 * ks + 1][ntl]), lo, hi, oa, ob);
            pfrag[ntl] = mkfrag(oa, ob);
        }
        bf16x8 vb[2];
        #pragma unroll
        for (int dt = 0; dt < 2; ++dt)
            vb[dt] = *(const bf16x8*)swz128(Vh, dt * 16 + lo, (ks * 32 + hi * 8) * 2);
        #pragma unroll
        for (int ntl = 0; ntl < 2; ++ntl)
            #pragma unroll
            for (int dt = 0; dt < 2; ++dt)
                co[ntl][dt] = __builtin_amdgcn_mfma_f32_16x16x32_bf16(pfrag[ntl], vb[dt], co[ntl][dt], 0, 0, 0);
    }
    // scale: co row n = base+hi*4+r needs iv held at lane index (hi*4+r)
    #pragma unroll
    for (int ntl = 0; ntl < 2; ++ntl)
        #pragma unroll
        for (int r = 0; r < 4; ++r) {
            float sc = __shfl(iv[ntl], hi * 4 + r);
            co[ntl][0][r] *= sc;
            co[ntl][1][r] *= sc;
        }
    __syncthreads();   // b2: all XA reads (pass Q) complete before AO overlay

    // ---- AO overlays XA ----
    #pragma unroll
    for (int ntl = 0; ntl < 2; ++ntl)
        #pragma unroll
        for (int dt = 0; dt < 2; ++dt)
            #pragma unroll
            for (int r = 0; r < 4; ++r) {
                int n = (half * 2 + ntl) * 16 + hi * 4 + r;
                *(unsigned short*)swz384(XA, n, (h * 32 + dt * 16 + lo) * 2) =
                    f2b(co[ntl][dt][r]);
            }
    __syncthreads();   // b3: AO complete

    // ---- proj: out = AO . Wp^T + b (wave owns o-tile wv) ----
    f32x4 ac[4] = {};
    const int o2 = wv * 16 + lo;
    for (int ks = 0; ks < 6; ++ks) {
        bf16x8 bb = *(const bf16x8*)(const void*)(wp + o2 * CDIM + ks * 32 + hi * 8);
        #pragma unroll
        for (int nt = 0; nt < 4; ++nt) {
            bf16x8 aa = *(const bf16x8*)swz384(XA, nt * 16 + lo, (ks * 32 + hi * 8) * 2);
            ac[nt] = __builtin_amdgcn_mfma_f32_16x16x32_bf16(aa, bb, ac[nt], 0, 0, 0);
        }
    }
    float* outW = out + (size_t)w * (NTOK * CDIM);
    float pb = proj_b[o2];
    #pragma unroll
    for (int nt = 0; nt < 4; ++nt)
        #pragma unroll
        for (int r = 0; r < 4; ++r) {
            int n = nt * 16 + hi * 4 + r;
            outW[n * CDIM + o2] = ac[nt][r] + pb;
        }
}

extern "C" void kernel_launch(void* const* d_in, const int* in_sizes, int n_in,
                              void* d_out, int out_size, void* d_ws, size_t ws_size,
                              hipStream_t stream) {
    const float* x          = (const float*)d_in[0];
    const float* mask       = (const float*)d_in[1];
    const float* qkv_w      = (const float*)d_in[2];
    const float* qkv_b      = (const float*)d_in[3];
    const float* proj_w     = (const float*)d_in[4];
    const float* proj_b     = (const float*)d_in[5];
    const float* bias_table = (const float*)d_in[6];
    float* out = (float*)d_out;

    unsigned short* wq = (unsigned short*)d_ws;
    unsigned short* wp = wq + WQ_ELEMS;
    float* relb = (float*)((char*)d_ws + WS_RELB_OFF);

    const int nW = in_sizes[0] / (NTOK * CDIM);   // 4096
    const int use_relb = (ws_size >= (size_t)WS_NEED) ? 1 : 0;

    prep_weights<<<dim3((WQ_ELEMS + 255) / 256), dim3(256), 0, stream>>>(
        qkv_w, proj_w, bias_table, wq, wp, relb, use_relb);

    if (use_relb) {
        hipFuncSetAttribute(reinterpret_cast<const void*>(win_attn<true>),
                            hipFuncAttributeMaxDynamicSharedMemorySize, LDS_BYTES);
        win_attn<true><<<dim3(nW), dim3(NTHR), LDS_BYTES, stream>>>(
            x, mask, wq, qkv_b, wp, proj_b, bias_table, relb, out);
    } else {
        hipFuncSetAttribute(reinterpret_cast<const void*>(win_attn<false>),
                            hipFuncAttributeMaxDynamicSharedMemorySize, LDS_BYTES);
        win_attn<false><<<dim3(nW), dim3(NTHR), LDS_BYTES, stream>>>(
            x, mask, wq, qkv_b, wp, proj_b, bias_table, relb, out);
    }
}